// Round 2
// baseline (143.824 us; speedup 1.0000x reference)
//
#include <hip/hip_runtime.h>

// PositionAwareARCEncoder fused kernels.
// B=32768, H=W=5, NC=4, E=64, HID=128, OUT=128, NH=4, HD=16.
//
// Table factorization:
//  inpval[c][ij][64]  = input-MLP(concat(color_embed[c], pos[ij]))
//  ktab[c][ij][64]    = inpval @ k_w + k_b
//  vtab[c][ij][64]    = inpval @ v_w + v_b
//  outval[c][ij][64]  = output-MLP(concat(color_embed[c], pos[ij]))
//  outproj[c][ij][128]= (outval @ cb_w1[64:128]) / 25
//  qtab[p][64]        = cpe(p) @ q_w + q_b          (p=25 -> cpe=0 -> q_b)
//  cpeproj[p][128]    = cpe(p) @ cb_w1[128:192]     (p=25 -> 0)
//  wov[64][128]       = o_w @ cb_w1[0:64]
//  bias1[128]         = cb_b1 + o_b @ cb_w1[0:64]
//  stab[cpe][ig][ij][h] = (qtab[cpe] . ktab[ig,ij])_head_h * HD^-0.5   (NEW)

__global__ void prep12(const float* __restrict__ color_embed,
                       const float* __restrict__ row_embed,
                       const float* __restrict__ col_embed,
                       const float* __restrict__ ip_w1, const float* __restrict__ ip_b1,
                       const float* __restrict__ ip_w2, const float* __restrict__ ip_b2,
                       const float* __restrict__ op_w1, const float* __restrict__ op_b1,
                       const float* __restrict__ op_w2, const float* __restrict__ op_b2,
                       float* __restrict__ inpval, float* __restrict__ outval) {
  __shared__ float feat[128];
  __shared__ float h1[128];
  const int bid = blockIdx.x;       // 0..199
  const int path = bid / 100;       // 0: input MLP, 1: output MLP
  const int cij = bid % 100;
  const int c = cij / 25, ij = cij % 25, gi = ij / 5, gj = ij % 5;
  const int t = threadIdx.x;        // 128 threads
  if (t < 64)      feat[t] = color_embed[c * 64 + t];
  else if (t < 96) feat[t] = row_embed[gi * 32 + (t - 64)];
  else             feat[t] = col_embed[gj * 32 + (t - 96)];
  __syncthreads();
  const float* w1 = path ? op_w1 : ip_w1;
  const float* b1 = path ? op_b1 : ip_b1;
  float acc = b1[t];
#pragma unroll 8
  for (int d = 0; d < 128; ++d) acc = fmaf(feat[d], w1[d * 128 + t], acc);
  h1[t] = fmaxf(acc, 0.f);
  __syncthreads();
  if (t < 64) {
    const float* w2 = path ? op_w2 : ip_w2;
    const float* b2 = path ? op_b2 : ip_b2;
    float v = b2[t];
#pragma unroll 8
    for (int d = 0; d < 128; ++d) v = fmaf(h1[d], w2[d * 64 + t], v);
    (path ? outval : inpval)[cij * 64 + t] = v;
  }
}

__global__ void prep3(const float* __restrict__ row_embed, const float* __restrict__ col_embed,
                      const float* __restrict__ k_w, const float* __restrict__ k_b,
                      const float* __restrict__ v_w, const float* __restrict__ v_b,
                      const float* __restrict__ q_w, const float* __restrict__ q_b,
                      const float* __restrict__ o_w, const float* __restrict__ o_b,
                      const float* __restrict__ cb_w1, const float* __restrict__ cb_b1,
                      const float* __restrict__ inpval, const float* __restrict__ outval,
                      float* __restrict__ ktab, float* __restrict__ vtab,
                      float* __restrict__ outproj, float* __restrict__ qtab,
                      float* __restrict__ cpeproj, float* __restrict__ wov,
                      float* __restrict__ bias1) {
  const int tid = blockIdx.x * 256 + threadIdx.x;
  if (tid < 6400) {                       // ktab[100][64]
    const int cij = tid >> 6, e2 = tid & 63;
    const float* x = inpval + cij * 64;
    float a = k_b[e2];
#pragma unroll 8
    for (int e = 0; e < 64; ++e) a = fmaf(x[e], k_w[e * 64 + e2], a);
    ktab[tid] = a;
  } else if (tid < 12800) {               // vtab[100][64]
    const int l = tid - 6400;
    const int cij = l >> 6, e2 = l & 63;
    const float* x = inpval + cij * 64;
    float a = v_b[e2];
#pragma unroll 8
    for (int e = 0; e < 64; ++e) a = fmaf(x[e], v_w[e * 64 + e2], a);
    vtab[l] = a;
  } else if (tid < 25600) {               // outproj[100][128] (1/25 folded)
    const int l = tid - 12800;
    const int cij = l >> 7, jj = l & 127;
    const float* x = outval + cij * 64;
    float a = 0.f;
#pragma unroll 8
    for (int e = 0; e < 64; ++e) a = fmaf(x[e], cb_w1[(64 + e) * 128 + jj], a);
    outproj[l] = a * (1.f / 25.f);
  } else if (tid < 27264) {               // qtab[26][64]
    const int l = tid - 25600;
    const int p = l >> 6, e2 = l & 63;
    float a = q_b[e2];
    if (p < 25) {
      const int r = p / 5, c = p % 5;
#pragma unroll 8
      for (int e = 0; e < 32; ++e) a = fmaf(row_embed[r * 32 + e], q_w[e * 64 + e2], a);
#pragma unroll 8
      for (int e = 0; e < 32; ++e) a = fmaf(col_embed[c * 32 + e], q_w[(32 + e) * 64 + e2], a);
    }
    qtab[l] = a;
  } else if (tid < 30592) {               // cpeproj[26][128]
    const int l = tid - 27264;
    const int p = l >> 7, jj = l & 127;
    float a = 0.f;
    if (p < 25) {
      const int r = p / 5, c = p % 5;
#pragma unroll 8
      for (int e = 0; e < 32; ++e) a = fmaf(row_embed[r * 32 + e], cb_w1[(128 + e) * 128 + jj], a);
#pragma unroll 8
      for (int e = 0; e < 32; ++e) a = fmaf(col_embed[c * 32 + e], cb_w1[(160 + e) * 128 + jj], a);
    }
    cpeproj[l] = a;
  } else if (tid < 38784) {               // wov[64][128]
    const int l = tid - 30592;
    const int d = l >> 7, jj = l & 127;
    float a = 0.f;
#pragma unroll 8
    for (int e = 0; e < 64; ++e) a = fmaf(o_w[d * 64 + e], cb_w1[e * 128 + jj], a);
    wov[l] = a;
  } else if (tid < 38912) {               // bias1[128]
    const int jj = tid - 38784;
    float a = cb_b1[jj];
#pragma unroll 8
    for (int e = 0; e < 64; ++e) a = fmaf(o_b[e], cb_w1[e * 128 + jj], a);
    bias1[jj] = a;
  }
}

// stab[cpe][ig][ij][h] — must run AFTER prep3 (reads qtab/ktab).
__global__ void prep4(const float* __restrict__ qtab, const float* __restrict__ ktab,
                      float* __restrict__ stab) {
  const int tid = blockIdx.x * 256 + threadIdx.x;
  if (tid >= 10400) return;
  const int h = tid & 3;
  const int ij = (tid >> 2) % 25;
  const int ig = ((tid >> 2) / 25) & 3;
  const int cpe = (tid >> 2) / 100;
  const float* qq = qtab + cpe * 64 + h * 16;
  const float* kk = ktab + (ig * 25 + ij) * 64 + h * 16;
  float a = 0.f;
#pragma unroll
  for (int d = 0; d < 16; ++d) a = fmaf(qq[d], kk[d], a);
  stab[tid] = a * 0.25f;   // HD^-0.5 folded in
}

// One wave = 2 batch elements. Phase A: ballots + table lookups + softmax.
// Phase 2: two dense layers, lane = column pair (2L, 2L+1), ra/hidden
// broadcast via uniform-address ds_read_b128 (no shuffles).
__global__ __launch_bounds__(256) void arc_main(
    const int* __restrict__ obs,
    const float* __restrict__ stab, const float* __restrict__ vtab,
    const float* __restrict__ outproj, const float* __restrict__ cpeproj,
    const float* __restrict__ wov, const float* __restrict__ bias1,
    const float* __restrict__ cb_w2, const float* __restrict__ cb_b2,
    float* __restrict__ out) {
  __shared__ float lds_ra[4][2][64];
  __shared__ float lds_h[4][2][128];
  const int lane = threadIdx.x & 63;
  const int wv = threadIdx.x >> 6;
  const int h = lane >> 4;
  const int b0 = blockIdx.x * 8 + wv * 2;
  float acc[4];   // hidden accumulators: [e*2 + col]

#pragma unroll
  for (int e = 0; e < 2; ++e) {
    const int* ob = obs + (b0 + e) * 75;
    const int x = ob[lane];
    const int y = (lane < 11) ? ob[64 + lane] : 0;
    const unsigned long long ig_lo = __ballot((lane < 25) && (x & 1));
    const unsigned long long ig_hi = __ballot((lane < 25) && (x & 2));
    const unsigned long long og_lo = __ballot((lane >= 25) && (lane < 50) && (x & 1)) >> 25;
    const unsigned long long og_hi = __ballot((lane >= 25) && (lane < 50) && (x & 2)) >> 25;
    const unsigned long long mb =
        (__ballot((lane >= 50) && (x != 0)) >> 50) |
        (__ballot((lane < 11) && (y != 0)) << 14);
    const int cpe_idx = mb ? __builtin_ctzll((long long)mb) : 25;

    // scores from the precomputed table (16-lane broadcast loads)
    const float* sbase = stab + cpe_idx * 400 + h;
    float sc[25];
    float mx = -1e30f;
#pragma unroll
    for (int ij = 0; ij < 25; ++ij) {
      const int ig = (int)((ig_lo >> ij) & 1ull) | ((int)((ig_hi >> ij) & 1ull) << 1);
      sc[ij] = sbase[ig * 100 + ij * 4];
      mx = fmaxf(mx, sc[ij]);
    }
    float s = 0.f;
#pragma unroll
    for (int ij = 0; ij < 25; ++ij) { sc[ij] = __expf(sc[ij] - mx); s += sc[ij]; }
    const float inv = 1.0f / s;

    float ra = 0.f;
#pragma unroll
    for (int ij = 0; ij < 25; ++ij) {
      const int ig = (int)((ig_lo >> ij) & 1ull) | ((int)((ig_hi >> ij) & 1ull) << 1);
      ra = fmaf(sc[ij], vtab[(ig * 25 + ij) * 64 + lane], ra);
    }
    lds_ra[wv][e][lane] = ra * inv;

    float2 a2 = ((const float2*)bias1)[lane];
    const float2 cp = ((const float2*)cpeproj)[cpe_idx * 64 + lane];
    a2.x += cp.x; a2.y += cp.y;
#pragma unroll
    for (int ij = 0; ij < 25; ++ij) {
      const int og = (int)((og_lo >> ij) & 1ull) | ((int)((og_hi >> ij) & 1ull) << 1);
      const float2 p = ((const float2*)outproj)[(og * 25 + ij) * 64 + lane];
      a2.x += p.x; a2.y += p.y;
    }
    acc[e * 2]     = a2.x;
    acc[e * 2 + 1] = a2.y;
  }

  __syncthreads();

  // hidden += ra @ wov ; lane holds cols (2L, 2L+1) for both batch elems
  const float2* wov2 = (const float2*)wov;
#pragma unroll 4
  for (int d0 = 0; d0 < 64; d0 += 4) {
    const float4 r0 = *(const float4*)&lds_ra[wv][0][d0];   // uniform addr: broadcast
    const float4 r1 = *(const float4*)&lds_ra[wv][1][d0];
    const float rr0[4] = {r0.x, r0.y, r0.z, r0.w};
    const float rr1[4] = {r1.x, r1.y, r1.z, r1.w};
#pragma unroll
    for (int t = 0; t < 4; ++t) {
      const float2 w = wov2[(d0 + t) * 64 + lane];
      acc[0] = fmaf(rr0[t], w.x, acc[0]);
      acc[1] = fmaf(rr0[t], w.y, acc[1]);
      acc[2] = fmaf(rr1[t], w.x, acc[2]);
      acc[3] = fmaf(rr1[t], w.y, acc[3]);
    }
  }
  const float2 h0 = make_float2(fmaxf(acc[0], 0.f), fmaxf(acc[1], 0.f));
  const float2 h1 = make_float2(fmaxf(acc[2], 0.f), fmaxf(acc[3], 0.f));
  *(float2*)&lds_h[wv][0][2 * lane] = h0;
  *(float2*)&lds_h[wv][1][2 * lane] = h1;

  __syncthreads();

  // out = hidden @ cb_w2 + cb_b2
  const float2 bb = ((const float2*)cb_b2)[lane];
  float o0 = bb.x, o1 = bb.y, o2 = bb.x, o3 = bb.y;
  const float2* w22 = (const float2*)cb_w2;
#pragma unroll 4
  for (int j0 = 0; j0 < 128; j0 += 4) {
    const float4 q0 = *(const float4*)&lds_h[wv][0][j0];    // uniform addr: broadcast
    const float4 q1 = *(const float4*)&lds_h[wv][1][j0];
    const float qq0[4] = {q0.x, q0.y, q0.z, q0.w};
    const float qq1[4] = {q1.x, q1.y, q1.z, q1.w};
#pragma unroll
    for (int t = 0; t < 4; ++t) {
      const float2 w = w22[(j0 + t) * 64 + lane];
      o0 = fmaf(qq0[t], w.x, o0);
      o1 = fmaf(qq0[t], w.y, o1);
      o2 = fmaf(qq1[t], w.x, o2);
      o3 = fmaf(qq1[t], w.y, o3);
    }
  }
  ((float2*)out)[b0 * 64 + lane]       = make_float2(o0, o1);
  ((float2*)out)[(b0 + 1) * 64 + lane] = make_float2(o2, o3);
}

extern "C" void kernel_launch(void* const* d_in, const int* in_sizes, int n_in,
                              void* d_out, int out_size, void* d_ws, size_t ws_size,
                              hipStream_t stream) {
  const int*   obs         = (const int*)d_in[0];
  const float* color_embed = (const float*)d_in[1];
  const float* row_embed   = (const float*)d_in[2];
  const float* col_embed   = (const float*)d_in[3];
  const float* ip_w1 = (const float*)d_in[4];
  const float* ip_b1 = (const float*)d_in[5];
  const float* ip_w2 = (const float*)d_in[6];
  const float* ip_b2 = (const float*)d_in[7];
  const float* q_w = (const float*)d_in[8];
  const float* q_b = (const float*)d_in[9];
  const float* k_w = (const float*)d_in[10];
  const float* k_b = (const float*)d_in[11];
  const float* v_w = (const float*)d_in[12];
  const float* v_b = (const float*)d_in[13];
  const float* o_w = (const float*)d_in[14];
  const float* o_b = (const float*)d_in[15];
  const float* op_w1 = (const float*)d_in[16];
  const float* op_b1 = (const float*)d_in[17];
  const float* op_w2 = (const float*)d_in[18];
  const float* op_b2 = (const float*)d_in[19];
  const float* cb_w1 = (const float*)d_in[20];
  const float* cb_b1 = (const float*)d_in[21];
  const float* cb_w2 = (const float*)d_in[22];
  const float* cb_b2 = (const float*)d_in[23];

  float* ws = (float*)d_ws;
  float* qtab    = ws;               // 26*64   = 1664
  float* cpeproj = qtab + 1664;      // 26*128  = 3328
  float* ktab    = cpeproj + 3328;   // 100*64  = 6400
  float* vtab    = ktab + 6400;      // 100*64  = 6400
  float* outproj = vtab + 6400;      // 100*128 = 12800
  float* wov     = outproj + 12800;  // 64*128  = 8192
  float* bias1   = wov + 8192;       // 128
  float* inpval  = bias1 + 128;      // 100*64  = 6400
  float* outval  = inpval + 6400;    // 100*64  = 6400
  float* stab    = outval + 6400;    // 26*4*25*4 = 10400
  // total 62112 floats ≈ 248 KB of d_ws

  prep12<<<200, 128, 0, stream>>>(color_embed, row_embed, col_embed,
                                  ip_w1, ip_b1, ip_w2, ip_b2,
                                  op_w1, op_b1, op_w2, op_b2, inpval, outval);
  prep3<<<152, 256, 0, stream>>>(row_embed, col_embed, k_w, k_b, v_w, v_b,
                                 q_w, q_b, o_w, o_b, cb_w1, cb_b1,
                                 inpval, outval,
                                 ktab, vtab, outproj, qtab, cpeproj, wov, bias1);
  prep4<<<41, 256, 0, stream>>>(qtab, ktab, stab);
  arc_main<<<4096, 256, 0, stream>>>(obs, stab, vtab, outproj, cpeproj,
                                     wov, bias1, cb_w2, cb_b2, (float*)d_out);
}

// Round 4
// 83.946 us; speedup vs baseline: 1.7133x; 1.7133x over previous
//
#include <hip/hip_runtime.h>

// PositionAwareARCEncoder fused kernels.
// B=32768, H=W=5, NC=4, E=64, HID=128, OUT=128, NH=4, HD=16.
//
// Table factorization (all built once in d_ws, ~300 KB total):
//  inpval[c][ij][64]  = input-MLP(concat(color_embed[c], pos[ij]))
//  ktab/vtab[c][ij][64] = inpval @ {k,v}_w + b
//  outval[c][ij][64]  = output-MLP(...)
//  outproj[c][ij][128]= (outval @ cb_w1[64:128]) / 25
//  qtab[p][64], cpeproj[p][128]  (p=25 -> cpe=0)
//  wov[64][128] = o_w @ cb_w1[0:64];  bias1 = cb_b1 + o_b @ cb_w1[0:64]
//  stab[cpe][ig][ij][h] = per-head q.k * HD^-0.5
//  wovT/cbw2T bf16 transposed for MFMA B-fragments
//
// arc_fused: block = 16 batches = 4 waves.
//  Phase A (per wave, 4 batches): ballot decode -> stab lookups -> softmax ->
//    ra (bf16 hi+lo, swizzled) + pre (fp32) into LDS.
//  Phase B: hidden = relu(pre + ra@wov) via MFMA (hi/lo compensated),
//    out = hidden@cb_w2 + b2 via MFMA with cb_w2 staged in swizzled LDS.
//    Column-tiles nt = wv*2, wv*2+1 per wave.

typedef __attribute__((ext_vector_type(8))) short short8v;
typedef __attribute__((ext_vector_type(4))) float float4v;

static __device__ __forceinline__ unsigned short f2bf(float f) {
  unsigned int u = __float_as_uint(f);
  unsigned int r = (u + 0x7fffu + ((u >> 16) & 1u)) >> 16;
  return (unsigned short)r;
}
static __device__ __forceinline__ float bf2f(unsigned short s) {
  return __uint_as_float(((unsigned int)s) << 16);
}

__global__ void prep12(const float* __restrict__ color_embed,
                       const float* __restrict__ row_embed,
                       const float* __restrict__ col_embed,
                       const float* __restrict__ ip_w1, const float* __restrict__ ip_b1,
                       const float* __restrict__ ip_w2, const float* __restrict__ ip_b2,
                       const float* __restrict__ op_w1, const float* __restrict__ op_b1,
                       const float* __restrict__ op_w2, const float* __restrict__ op_b2,
                       float* __restrict__ inpval, float* __restrict__ outval) {
  __shared__ float feat[128];
  __shared__ float h1[128];
  const int bid = blockIdx.x;       // 0..199
  const int path = bid / 100;
  const int cij = bid % 100;
  const int c = cij / 25, ij = cij % 25, gi = ij / 5, gj = ij % 5;
  const int t = threadIdx.x;        // 128 threads
  if (t < 64)      feat[t] = color_embed[c * 64 + t];
  else if (t < 96) feat[t] = row_embed[gi * 32 + (t - 64)];
  else             feat[t] = col_embed[gj * 32 + (t - 96)];
  __syncthreads();
  const float* w1 = path ? op_w1 : ip_w1;
  const float* b1 = path ? op_b1 : ip_b1;
  float acc = b1[t];
#pragma unroll 8
  for (int d = 0; d < 128; ++d) acc = fmaf(feat[d], w1[d * 128 + t], acc);
  h1[t] = fmaxf(acc, 0.f);
  __syncthreads();
  if (t < 64) {
    const float* w2 = path ? op_w2 : ip_w2;
    const float* b2 = path ? op_b2 : ip_b2;
    float v = b2[t];
#pragma unroll 8
    for (int d = 0; d < 128; ++d) v = fmaf(h1[d], w2[d * 64 + t], v);
    (path ? outval : inpval)[cij * 64 + t] = v;
  }
}

__global__ void prep3(const float* __restrict__ row_embed, const float* __restrict__ col_embed,
                      const float* __restrict__ k_w, const float* __restrict__ k_b,
                      const float* __restrict__ v_w, const float* __restrict__ v_b,
                      const float* __restrict__ q_w, const float* __restrict__ q_b,
                      const float* __restrict__ o_w, const float* __restrict__ o_b,
                      const float* __restrict__ cb_w1, const float* __restrict__ cb_b1,
                      const float* __restrict__ inpval, const float* __restrict__ outval,
                      float* __restrict__ ktab, float* __restrict__ vtab,
                      float* __restrict__ outproj, float* __restrict__ qtab,
                      float* __restrict__ cpeproj, float* __restrict__ wov,
                      float* __restrict__ bias1) {
  const int tid = blockIdx.x * 256 + threadIdx.x;
  if (tid < 6400) {                       // ktab[100][64]
    const int cij = tid >> 6, e2 = tid & 63;
    const float* x = inpval + cij * 64;
    float a = k_b[e2];
#pragma unroll 8
    for (int e = 0; e < 64; ++e) a = fmaf(x[e], k_w[e * 64 + e2], a);
    ktab[tid] = a;
  } else if (tid < 12800) {               // vtab[100][64]
    const int l = tid - 6400;
    const int cij = l >> 6, e2 = l & 63;
    const float* x = inpval + cij * 64;
    float a = v_b[e2];
#pragma unroll 8
    for (int e = 0; e < 64; ++e) a = fmaf(x[e], v_w[e * 64 + e2], a);
    vtab[l] = a;
  } else if (tid < 25600) {               // outproj[100][128] (1/25 folded)
    const int l = tid - 12800;
    const int cij = l >> 7, jj = l & 127;
    const float* x = outval + cij * 64;
    float a = 0.f;
#pragma unroll 8
    for (int e = 0; e < 64; ++e) a = fmaf(x[e], cb_w1[(64 + e) * 128 + jj], a);
    outproj[l] = a * (1.f / 25.f);
  } else if (tid < 27264) {               // qtab[26][64]
    const int l = tid - 25600;
    const int p = l >> 6, e2 = l & 63;
    float a = q_b[e2];
    if (p < 25) {
      const int r = p / 5, c = p % 5;
#pragma unroll 8
      for (int e = 0; e < 32; ++e) a = fmaf(row_embed[r * 32 + e], q_w[e * 64 + e2], a);
#pragma unroll 8
      for (int e = 0; e < 32; ++e) a = fmaf(col_embed[c * 32 + e], q_w[(32 + e) * 64 + e2], a);
    }
    qtab[l] = a;
  } else if (tid < 30592) {               // cpeproj[26][128]
    const int l = tid - 27264;
    const int p = l >> 7, jj = l & 127;
    float a = 0.f;
    if (p < 25) {
      const int r = p / 5, c = p % 5;
#pragma unroll 8
      for (int e = 0; e < 32; ++e) a = fmaf(row_embed[r * 32 + e], cb_w1[(128 + e) * 128 + jj], a);
#pragma unroll 8
      for (int e = 0; e < 32; ++e) a = fmaf(col_embed[c * 32 + e], cb_w1[(160 + e) * 128 + jj], a);
    }
    cpeproj[l] = a;
  } else if (tid < 38784) {               // wov[64][128]
    const int l = tid - 30592;
    const int d = l >> 7, jj = l & 127;
    float a = 0.f;
#pragma unroll 8
    for (int e = 0; e < 64; ++e) a = fmaf(o_w[d * 64 + e], cb_w1[e * 128 + jj], a);
    wov[l] = a;
  } else if (tid < 38912) {               // bias1[128]
    const int jj = tid - 38784;
    float a = cb_b1[jj];
#pragma unroll 8
    for (int e = 0; e < 64; ++e) a = fmaf(o_b[e], cb_w1[e * 128 + jj], a);
    bias1[jj] = a;
  }
}

// stab[cpe][ig][ij][h]
__global__ void prep4(const float* __restrict__ qtab, const float* __restrict__ ktab,
                      float* __restrict__ stab) {
  const int tid = blockIdx.x * 256 + threadIdx.x;
  if (tid >= 10400) return;
  const int h = tid & 3;
  const int ij = (tid >> 2) % 25;
  const int ig = ((tid >> 2) / 25) & 3;
  const int cpe = (tid >> 2) / 100;
  const float* qq = qtab + cpe * 64 + h * 16;
  const float* kk = ktab + (ig * 25 + ij) * 64 + h * 16;
  float a = 0.f;
#pragma unroll
  for (int d = 0; d < 16; ++d) a = fmaf(qq[d], kk[d], a);
  stab[tid] = a * 0.25f;
}

// bf16 transposed weights: wovT[col 128][k 64], cbw2T[col 128][k 128]
__global__ void prep5(const float* __restrict__ wov, const float* __restrict__ cb_w2,
                      unsigned short* __restrict__ wovT, unsigned short* __restrict__ cbw2T) {
  const int tid = blockIdx.x * 256 + threadIdx.x;
  if (tid < 8192) {
    const int j = tid >> 6, d = tid & 63;
    wovT[tid] = f2bf(wov[d * 128 + j]);
  } else if (tid < 24576) {
    const int t = tid - 8192;
    const int j = t >> 7, k = t & 127;
    cbw2T[t] = f2bf(cb_w2[k * 128 + j]);
  }
}

__global__ __launch_bounds__(256) void arc_fused(
    const int* __restrict__ obs,
    const float* __restrict__ stab, const float* __restrict__ vtab,
    const float* __restrict__ outproj, const float* __restrict__ cpeproj,
    const float* __restrict__ bias1,
    const unsigned short* __restrict__ wovT, const unsigned short* __restrict__ cbw2T,
    const float* __restrict__ cb_b2, float* __restrict__ out) {
  __shared__ short cbs[16384];       // cb_w2^T bf16, [col 128][k 128], XOR-swizzled
  __shared__ float lds_pre[16][132]; // pre-activation, +4 pad breaks bank alignment
  __shared__ short lds_raH[1024];    // ra hi bf16 [16][64], swizzled
  __shared__ short lds_raL[1024];    // ra lo
  __shared__ short lds_hidH[2048];   // hidden hi bf16 [16][128], swizzled
  __shared__ short lds_hidL[2048];   // hidden lo

  const int tid = threadIdx.x;
  const int lane = tid & 63, wv = tid >> 6;
  const int row16 = lane & 15, g4 = lane >> 4;
  const int bbase = blockIdx.x * 16;

  // Stage cb_w2^T into LDS (swizzle: byte ^= (col&7)<<4). Hidden under phase A.
#pragma unroll
  for (int it = 0; it < 8; ++it) {
    const int c = tid + it * 256;          // chunk of 8 bf16
    const int col = c >> 4, k8 = c & 15;
    const int dstB = (col * 256 + k8 * 16) ^ ((col & 7) << 4);
    *(short8v*)((char*)cbs + dstB) = *(const short8v*)(cbw2T + c * 8);
  }

  // ---------------- phase A: 4 batches per wave ----------------
#pragma unroll 2
  for (int e = 0; e < 4; ++e) {
    const int r = wv * 4 + e;              // local row 0..15
    const int b = bbase + r;
    const int* ob = obs + b * 75;
    const int x = ob[lane];
    const int y = (lane < 11) ? ob[64 + lane] : 0;
    const unsigned long long ig_lo = __ballot((lane < 25) && (x & 1));
    const unsigned long long ig_hi = __ballot((lane < 25) && (x & 2));
    const unsigned long long og_lo = __ballot((lane >= 25) && (lane < 50) && (x & 1)) >> 25;
    const unsigned long long og_hi = __ballot((lane >= 25) && (lane < 50) && (x & 2)) >> 25;
    const unsigned long long mb =
        (__ballot((lane >= 50) && (x != 0)) >> 50) |
        (__ballot((lane < 11) && (y != 0)) << 14);
    const int cpe_idx = mb ? __builtin_ctzll((long long)mb) : 25;

    // scores: wave-uniform float4 loads, select head component (head = g4)
    const int sb = __builtin_amdgcn_readfirstlane(cpe_idx * 400);
    float sc[25];
    float mx = -1e30f;
#pragma unroll
    for (int ij = 0; ij < 25; ++ij) {
      const int ig = (int)((ig_lo >> ij) & 1ull) | ((int)((ig_hi >> ij) & 1ull) << 1);
      const float4 s4 = *(const float4*)(stab + sb + ig * 100 + ij * 4);
      const float sv = (g4 < 2) ? (g4 == 0 ? s4.x : s4.y) : (g4 == 2 ? s4.z : s4.w);
      sc[ij] = sv;
      mx = fmaxf(mx, sv);
    }
    float s = 0.f;
#pragma unroll
    for (int ij = 0; ij < 25; ++ij) { sc[ij] = __expf(sc[ij] - mx); s += sc[ij]; }
    const float inv = 1.0f / s;

    float ra = 0.f;
#pragma unroll
    for (int ij = 0; ij < 25; ++ij) {
      const int ig = (int)((ig_lo >> ij) & 1ull) | ((int)((ig_hi >> ij) & 1ull) << 1);
      ra = fmaf(sc[ij], vtab[(ig * 25 + ij) * 64 + lane], ra);
    }
    ra *= inv;
    const unsigned short hi = f2bf(ra);
    const int raoff = (r * 128 + lane * 2) ^ ((r & 7) << 4);
    *(short*)((char*)lds_raH + raoff) = (short)hi;
    *(short*)((char*)lds_raL + raoff) = (short)f2bf(ra - bf2f(hi));

    // pre = bias1 + cpeproj[cpe] + sum_ij outproj[og(ij), ij]; lane -> cols 2l,2l+1
    float2 a2 = ((const float2*)bias1)[lane];
    const float2 cp = ((const float2*)cpeproj)[cpe_idx * 64 + lane];
    a2.x += cp.x; a2.y += cp.y;
#pragma unroll
    for (int ij = 0; ij < 25; ++ij) {
      const int og = (int)((og_lo >> ij) & 1ull) | ((int)((og_hi >> ij) & 1ull) << 1);
      const float2 p = ((const float2*)outproj)[(og * 25 + ij) * 64 + lane];
      a2.x += p.x; a2.y += p.y;
    }
    *(float2*)&lds_pre[r][2 * lane] = a2;
  }
  __syncthreads();

  // ---------------- phase B: MFMA dense layers ----------------
  // Wave wv owns column-tiles nt = wv*2, wv*2+1.
  const int rswz = (row16 & 7) << 4;
  const short8v aH0 = *(const short8v*)((char*)lds_raH + ((row16 * 128 + g4 * 16) ^ rswz));
  const short8v aH1 = *(const short8v*)((char*)lds_raH + ((row16 * 128 + 64 + g4 * 16) ^ rswz));
  const short8v aL0 = *(const short8v*)((char*)lds_raL + ((row16 * 128 + g4 * 16) ^ rswz));
  const short8v aL1 = *(const short8v*)((char*)lds_raL + ((row16 * 128 + 64 + g4 * 16) ^ rswz));

  float4v acc[2];
  short8v bw[2][2];
#pragma unroll
  for (int t = 0; t < 2; ++t) {
    const int nt = wv * 2 + t;
#pragma unroll
    for (int ks = 0; ks < 2; ++ks)
      bw[t][ks] = *(const short8v*)(wovT + (nt * 16 + row16) * 64 + ks * 32 + g4 * 8);
    // C-init from pre (C/D layout: col = lane&15, row = (lane>>4)*4 + reg)
#pragma unroll
    for (int rr = 0; rr < 4; ++rr)
      acc[t][rr] = lds_pre[g4 * 4 + rr][nt * 16 + row16];
  }
#pragma unroll
  for (int t = 0; t < 2; ++t) {
    acc[t] = __builtin_amdgcn_mfma_f32_16x16x32_bf16(aL0, bw[t][0], acc[t], 0, 0, 0);
    acc[t] = __builtin_amdgcn_mfma_f32_16x16x32_bf16(aL1, bw[t][1], acc[t], 0, 0, 0);
    acc[t] = __builtin_amdgcn_mfma_f32_16x16x32_bf16(aH0, bw[t][0], acc[t], 0, 0, 0);
    acc[t] = __builtin_amdgcn_mfma_f32_16x16x32_bf16(aH1, bw[t][1], acc[t], 0, 0, 0);
  }

  // relu -> hidden bf16 hi+lo into swizzled LDS
#pragma unroll
  for (int t = 0; t < 2; ++t) {
    const int col = (wv * 2 + t) * 16 + row16;
#pragma unroll
    for (int rr = 0; rr < 4; ++rr) {
      const int row = g4 * 4 + rr;
      const float hv = fmaxf(acc[t][rr], 0.f);
      const unsigned short hb = f2bf(hv);
      const int off = (row * 256 + col * 2) ^ ((row & 7) << 4);
      *(short*)((char*)lds_hidH + off) = (short)hb;
      *(short*)((char*)lds_hidL + off) = (short)f2bf(hv - bf2f(hb));
    }
  }
  __syncthreads();

  // out = hidden @ cb_w2 + b2
  short8v ahH[4], ahL[4];
#pragma unroll
  for (int ks = 0; ks < 4; ++ks) {
    const int off = (row16 * 256 + ks * 64 + g4 * 16) ^ rswz;
    ahH[ks] = *(const short8v*)((char*)lds_hidH + off);
    ahL[ks] = *(const short8v*)((char*)lds_hidL + off);
  }
#pragma unroll
  for (int t = 0; t < 2; ++t) {
    const int col = (wv * 2 + t) * 16 + row16;
    float4v c2 = {0.f, 0.f, 0.f, 0.f};
#pragma unroll
    for (int ks = 0; ks < 4; ++ks) {
      const int off = (col * 256 + ks * 64 + g4 * 16) ^ ((col & 7) << 4);
      const short8v bb = *(const short8v*)((char*)cbs + off);
      c2 = __builtin_amdgcn_mfma_f32_16x16x32_bf16(ahL[ks], bb, c2, 0, 0, 0);
      c2 = __builtin_amdgcn_mfma_f32_16x16x32_bf16(ahH[ks], bb, c2, 0, 0, 0);
    }
    const float bv = cb_b2[col];
#pragma unroll
    for (int rr = 0; rr < 4; ++rr)
      out[(bbase + g4 * 4 + rr) * 128 + col] = c2[rr] + bv;
  }
}

extern "C" void kernel_launch(void* const* d_in, const int* in_sizes, int n_in,
                              void* d_out, int out_size, void* d_ws, size_t ws_size,
                              hipStream_t stream) {
  const int*   obs         = (const int*)d_in[0];
  const float* color_embed = (const float*)d_in[1];
  const float* row_embed   = (const float*)d_in[2];
  const float* col_embed   = (const float*)d_in[3];
  const float* ip_w1 = (const float*)d_in[4];
  const float* ip_b1 = (const float*)d_in[5];
  const float* ip_w2 = (const float*)d_in[6];
  const float* ip_b2 = (const float*)d_in[7];
  const float* q_w = (const float*)d_in[8];
  const float* q_b = (const float*)d_in[9];
  const float* k_w = (const float*)d_in[10];
  const float* k_b = (const float*)d_in[11];
  const float* v_w = (const float*)d_in[12];
  const float* v_b = (const float*)d_in[13];
  const float* o_w = (const float*)d_in[14];
  const float* o_b = (const float*)d_in[15];
  const float* op_w1 = (const float*)d_in[16];
  const float* op_b1 = (const float*)d_in[17];
  const float* op_w2 = (const float*)d_in[18];
  const float* op_b2 = (const float*)d_in[19];
  const float* cb_w1 = (const float*)d_in[20];
  const float* cb_b1 = (const float*)d_in[21];
  const float* cb_w2 = (const float*)d_in[22];
  const float* cb_b2 = (const float*)d_in[23];

  float* ws = (float*)d_ws;
  float* qtab    = ws;                 // 1664
  float* cpeproj = qtab + 1664;        // 3328
  float* ktab    = cpeproj + 3328;     // 6400
  float* vtab    = ktab + 6400;        // 6400
  float* outproj = vtab + 6400;        // 12800
  float* wov     = outproj + 12800;    // 8192
  float* bias1   = wov + 8192;         // 128
  float* inpval  = bias1 + 128;        // 6400
  float* outval  = inpval + 6400;      // 6400
  float* stab    = outval + 6400;      // 10400  (ends at 62112)
  unsigned short* wovT  = (unsigned short*)(ws + 62112);   // 8192 shorts
  unsigned short* cbw2T = (unsigned short*)(ws + 66208);   // 16384 shorts
  // total 74400 floats ≈ 298 KB of d_ws

  prep12<<<200, 128, 0, stream>>>(color_embed, row_embed, col_embed,
                                  ip_w1, ip_b1, ip_w2, ip_b2,
                                  op_w1, op_b1, op_w2, op_b2, inpval, outval);
  prep3<<<152, 256, 0, stream>>>(row_embed, col_embed, k_w, k_b, v_w, v_b,
                                 q_w, q_b, o_w, o_b, cb_w1, cb_b1,
                                 inpval, outval,
                                 ktab, vtab, outproj, qtab, cpeproj, wov, bias1);
  prep4<<<41, 256, 0, stream>>>(qtab, ktab, stab);
  prep5<<<96, 256, 0, stream>>>(wov, cb_w2, wovT, cbw2T);
  arc_fused<<<2048, 256, 0, stream>>>(obs, stab, vtab, outproj, cpeproj, bias1,
                                      wovT, cbw2T, cb_b2, (float*)d_out);
}